// Round 1
// baseline (24846.481 us; speedup 1.0000x reference)
//
#include <hip/hip_runtime.h>

typedef __attribute__((ext_vector_type(8))) short short8;
typedef __attribute__((ext_vector_type(4))) float f32x4;

static __device__ __forceinline__ float sigf(float x) { return 1.0f / (1.0f + expf(-x)); }

static __device__ __forceinline__ unsigned short f2b(float f) {
    unsigned int u = __float_as_uint(f);
    u += 0x7FFFu + ((u >> 16) & 1u);   // round-to-nearest-even
    return (unsigned short)(u >> 16);
}

// ---------------- utility kernels ----------------

__global__ __launch_bounds__(256) void k_zero(float* __restrict__ p, long n) {
    for (long i = (long)blockIdx.x * 256 + threadIdx.x; i < n; i += (long)gridDim.x * 256) p[i] = 0.0f;
}

__global__ __launch_bounds__(256) void k_gather(const float* __restrict__ table,
                                                const int* __restrict__ idx,
                                                float* __restrict__ out, long nrows) {
    long total = nrows * 300;
    for (long i = (long)blockIdx.x * 256 + threadIdx.x; i < total; i += (long)gridDim.x * 256) {
        long r = i / 300;
        long d = i - r * 300;
        out[i] = table[(long)idx[r] * 300 + d];
    }
}

__global__ __launch_bounds__(256) void k_f2b(const float4* __restrict__ src,
                                             ushort4* __restrict__ dst, long n4) {
    for (long i = (long)blockIdx.x * 256 + threadIdx.x; i < n4; i += (long)gridDim.x * 256) {
        float4 v = src[i];
        ushort4 u;
        u.x = f2b(v.x); u.y = f2b(v.y); u.z = f2b(v.z); u.w = f2b(v.w);
        dst[i] = u;
    }
}

// out[m][j] = sum_{k<300} X[m][k] * W[j][wstride* + koff + k] + bias[j]
// grid: (N/64, M/32), block 256
__global__ __launch_bounds__(256) void k_xw(const float* __restrict__ X,
                                            const float* __restrict__ W,
                                            int wstride, int koff,
                                            const float* __restrict__ bias,
                                            float* __restrict__ out, int N) {
    __shared__ float Xs[32][300];
    int m0 = blockIdx.y * 32;
    int j0 = blockIdx.x * 64;
    for (int i = threadIdx.x; i < 32 * 300; i += 256) {
        int r = i / 300, c = i - r * 300;
        Xs[r][c] = X[(long)(m0 + r) * 300 + c];
    }
    __syncthreads();
    int tx = threadIdx.x & 63, ty = threadIdx.x >> 6;
    int j = j0 + tx;
    const float* wr = W + (long)j * wstride + koff;
    float acc[8] = {0, 0, 0, 0, 0, 0, 0, 0};
    for (int k = 0; k < 300; ++k) {
        float w = wr[k];
#pragma unroll
        for (int mi = 0; mi < 8; ++mi) acc[mi] += Xs[ty * 8 + mi][k] * w;
    }
    float bv = bias[j];
#pragma unroll
    for (int mi = 0; mi < 8; ++mi)
        out[(long)(m0 + ty * 8 + mi) * N + j] = acc[mi] + bv;
}

// ---------------- encoder ----------------
// grid 128 (= 2 dirs x 16 j-blocks... actually 2 x 64 j-blocks of 8), block 256 = 32 b x 8 j
__global__ __launch_bounds__(256) void k_enc_step(const float* __restrict__ Xf,
                                                  const float* __restrict__ Xb,
                                                  const float* __restrict__ whhf,
                                                  const float* __restrict__ whhb,
                                                  const float* __restrict__ h_in,
                                                  float* __restrict__ h_out,
                                                  float* __restrict__ c_st,
                                                  float* __restrict__ enc_out, int t) {
    int dir = blockIdx.x >> 6;
    int jb = blockIdx.x & 63;
    int b = threadIdx.x >> 3;
    int j = (jb << 3) + (threadIdx.x & 7);
    const float* whh = dir ? whhb : whhf;
    const float* X = dir ? Xb : Xf;
    int s = dir ? (63 - t) : t;
    const float4* h4 = (const float4*)(h_in + ((dir << 5) + b) * 512);
    const float4* w0 = (const float4*)(whh + (long)j * 512);
    const float4* w1 = (const float4*)(whh + (long)(512 + j) * 512);
    const float4* w2 = (const float4*)(whh + (long)(1024 + j) * 512);
    const float4* w3 = (const float4*)(whh + (long)(1536 + j) * 512);
    float gi = 0, gf = 0, gg = 0, go = 0;
    for (int k = 0; k < 128; ++k) {
        float4 h = h4[k];
        float4 a = w0[k];
        gi += h.x * a.x + h.y * a.y + h.z * a.z + h.w * a.w;
        float4 bb = w1[k];
        gf += h.x * bb.x + h.y * bb.y + h.z * bb.z + h.w * bb.w;
        float4 cc = w2[k];
        gg += h.x * cc.x + h.y * cc.y + h.z * cc.z + h.w * cc.w;
        float4 dd = w3[k];
        go += h.x * dd.x + h.y * dd.y + h.z * dd.z + h.w * dd.w;
    }
    long sb = (long)s * 32 + b;
    const float* xr = X + sb * 2048;
    gi += xr[j]; gf += xr[512 + j]; gg += xr[1024 + j]; go += xr[1536 + j];
    int hi = ((dir << 5) + b) * 512 + j;
    float cv = c_st[hi];
    float c2 = sigf(gf) * cv + sigf(gi) * tanhf(gg);
    float h2 = sigf(go) * tanhf(c2);
    c_st[hi] = c2;
    h_out[hi] = h2;
    enc_out[sb * 1024 + (dir << 9) + j] = h2;
}

// hidden[b][2k+d] = h_enc_final[d][b][k] ; same for c
__global__ __launch_bounds__(256) void k_pack(const float* __restrict__ h_all,
                                              const float* __restrict__ c_all,
                                              float* __restrict__ hdec,
                                              float* __restrict__ cdec) {
    int i = blockIdx.x * 256 + threadIdx.x;
    if (i >= 32768) return;
    int b = i >> 10, jj = i & 1023, k = jj >> 1, d = jj & 1;
    hdec[i] = h_all[(d * 32 + b) * 512 + k];
    cdec[i] = c_all[(d * 32 + b) * 512 + k];
}

// ---------------- decoder per-step ----------------
// semi[b][j] = h[b] . attn_wi[j]   grid 64, block 256 (2 items each)
__global__ __launch_bounds__(256) void k_semi(const float* __restrict__ h,
                                              const float* __restrict__ wi,
                                              float* __restrict__ semi) {
    int jb = blockIdx.x;
#pragma unroll
    for (int rep = 0; rep < 2; ++rep) {
        int it = threadIdx.x + rep * 256;
        int b = it >> 4;
        int j = (jb << 4) + (it & 15);
        const float4* h4 = (const float4*)(h + b * 1024);
        const float4* w4 = (const float4*)(wi + (long)j * 1024);
        float acc = 0;
        for (int k = 0; k < 256; ++k) {
            float4 a = h4[k], w = w4[k];
            acc += a.x * w.x + a.y * w.y + a.z * w.z + a.w * w.w;
        }
        semi[b * 1024 + j] = acc;
    }
}

// per-batch attention: scores -> softmax(S=64) -> s_tilde.  grid 32, block 256
__global__ __launch_bounds__(256) void k_attn(const float* __restrict__ enc_out,
                                              const float* __restrict__ semi,
                                              float* __restrict__ s_tilde) {
    int b = blockIdx.x;
    __shared__ float red[256];
    __shared__ float sc[64];
    int s = threadIdx.x >> 2, part = threadIdx.x & 3;
    const float4* er = (const float4*)(enc_out + ((long)s * 32 + b) * 1024) + part * 64;
    const float4* sr = (const float4*)(semi + b * 1024) + part * 64;
    float acc = 0;
    for (int k = 0; k < 64; ++k) {
        float4 e = er[k], m = sr[k];
        acc += e.x * m.x + e.y * m.y + e.z * m.z + e.w * m.w;
    }
    red[threadIdx.x] = acc;
    __syncthreads();
    if (part == 0) sc[s] = red[s * 4] + red[s * 4 + 1] + red[s * 4 + 2] + red[s * 4 + 3];
    __syncthreads();
    if (threadIdx.x < 64) {
        float v = sc[threadIdx.x];
        float m = v;
        for (int off = 32; off; off >>= 1) m = fmaxf(m, __shfl_xor(m, off));
        float e = expf(v - m);
        float sum = e;
        for (int off = 32; off; off >>= 1) sum += __shfl_xor(sum, off);
        sc[threadIdx.x] = e / sum;
    }
    __syncthreads();
    int j0 = threadIdx.x * 4;
    float st0 = 0, st1 = 0, st2 = 0, st3 = 0;
    for (int s2 = 0; s2 < 64; ++s2) {
        float p = sc[s2];
        float4 e = *(const float4*)(enc_out + ((long)s2 * 32 + b) * 1024 + j0);
        st0 += p * e.x; st1 += p * e.y; st2 += p * e.z; st3 += p * e.w;
    }
    *(float4*)(s_tilde + b * 1024 + j0) = make_float4(st0, st1, st2, st3);
}

// c_t[b][j] = tanh(s_tilde[b].wo[j][0:1024] + h[b].wo[j][1024:2048])  grid 128, block 256
__global__ __launch_bounds__(256) void k_ct(const float* __restrict__ st,
                                            const float* __restrict__ h,
                                            const float* __restrict__ wo,
                                            float* __restrict__ ct) {
    int b = threadIdx.x >> 3;
    int j = blockIdx.x * 8 + (threadIdx.x & 7);
    const float4* s4 = (const float4*)(st + b * 1024);
    const float4* h4 = (const float4*)(h + b * 1024);
    const float4* wa = (const float4*)(wo + (long)j * 2048);
    const float4* wb = wa + 256;
    float acc = 0;
    for (int k = 0; k < 256; ++k) {
        float4 a = s4[k], w = wa[k];
        acc += a.x * w.x + a.y * w.y + a.z * w.z + a.w * w.w;
    }
    for (int k = 0; k < 256; ++k) {
        float4 a = h4[k], w = wb[k];
        acc += a.x * w.x + a.y * w.y + a.z * w.z + a.w * w.w;
    }
    ct[b * 1024 + j] = tanhf(acc);
}

// gates + LSTM cell; grid 256, block 256 = 128 items x 2 K-halves
__global__ __launch_bounds__(256) void k_dec_step(const float* __restrict__ ct,
                                                  const float* __restrict__ h_in,
                                                  float* __restrict__ c_st,
                                                  const float* __restrict__ Xe_t,
                                                  const float* __restrict__ wih,
                                                  const float* __restrict__ whh,
                                                  float* __restrict__ h_out,
                                                  unsigned short* __restrict__ hsb) {
    int half = threadIdx.x & 1;
    int item = threadIdx.x >> 1;  // 0..127
    int b = item >> 2;
    int j = blockIdx.x * 4 + (item & 3);
    const float4* x4 = (const float4*)((half ? h_in : ct) + b * 1024);
    float g[4];
#pragma unroll
    for (int gate = 0; gate < 4; ++gate) {
        long jg = (long)gate * 1024 + j;
        const float4* w4 = (const float4*)(half ? (whh + jg * 1024) : (wih + jg * 1324));
        float acc = 0;
        for (int k = 0; k < 256; ++k) {
            float4 a = x4[k], w = w4[k];
            acc += a.x * w.x + a.y * w.y + a.z * w.z + a.w * w.w;
        }
        g[gate] = acc;
    }
    __shared__ float gs[128][4];
    if (half) {
        gs[item][0] = g[0]; gs[item][1] = g[1]; gs[item][2] = g[2]; gs[item][3] = g[3];
    }
    __syncthreads();
    if (!half) {
        const float* xe = Xe_t + b * 4096;
        float gi = g[0] + gs[item][0] + xe[j];
        float gf = g[1] + gs[item][1] + xe[1024 + j];
        float gg = g[2] + gs[item][2] + xe[2048 + j];
        float go = g[3] + gs[item][3] + xe[3072 + j];
        int hi = b * 1024 + j;
        float cv = c_st[hi];
        float c2 = sigf(gf) * cv + sigf(gi) * tanhf(gg);
        float h2 = sigf(go) * tanhf(c2);
        c_st[hi] = c2;
        h_out[hi] = h2;
        hsb[hi] = f2b(h2);
    }
}

// ---------------- generator GEMM (bf16 MFMA) ----------------
// logits[m][n] = sum_k Hs[m][k] * gen_w[n][k],  M=2048 (2016 valid), N=32000, K=1024
// wave computes a 64x64 tile; block = 4 waves = 4 consecutive m-tiles, same n-panel.
__global__ __launch_bounds__(256) void k_gemm_gen(const short* __restrict__ A,
                                                  const short* __restrict__ B,
                                                  const float* __restrict__ genb,
                                                  float* __restrict__ out) {
    int wave = threadIdx.x >> 6;
    int lane = threadIdx.x & 63;
    int tile = blockIdx.x * 4 + wave;  // 16000 tiles = 32 m x 500 n
    int mt = tile & 31;
    int nt = tile >> 5;
    int m0 = mt * 64, n0 = nt * 64;
    int lr = lane & 15;
    int lk = (lane >> 4) * 8;
    f32x4 acc[4][4] = {};
    for (int k0 = 0; k0 < 1024; k0 += 32) {
        short8 a[4], bfr[4];
#pragma unroll
        for (int mi = 0; mi < 4; ++mi)
            a[mi] = *(const short8*)(A + (long)(m0 + mi * 16 + lr) * 1024 + k0 + lk);
#pragma unroll
        for (int ni = 0; ni < 4; ++ni)
            bfr[ni] = *(const short8*)(B + (long)(n0 + ni * 16 + lr) * 1024 + k0 + lk);
#pragma unroll
        for (int mi = 0; mi < 4; ++mi)
#pragma unroll
            for (int ni = 0; ni < 4; ++ni)
                acc[mi][ni] = __builtin_amdgcn_mfma_f32_16x16x32_bf16(a[mi], bfr[ni], acc[mi][ni], 0, 0, 0);
    }
    int dcol = lane & 15;
    int drow = (lane >> 4) * 4;
#pragma unroll
    for (int mi = 0; mi < 4; ++mi) {
        int mbase = m0 + mi * 16 + drow;
#pragma unroll
        for (int ni = 0; ni < 4; ++ni) {
            int n = n0 + ni * 16 + dcol;
            float bv = genb[n];
            f32x4 v = acc[mi][ni];
#pragma unroll
            for (int r = 0; r < 4; ++r) {
                int m = mbase + r;
                if (m < 2016) out[(long)(m + 32) * 32000 + n] = v[r] + bv;
            }
        }
    }
}

// in-place log-softmax on d_out rows 32..2047 (32000 wide). grid 2016, block 256
__global__ __launch_bounds__(256) void k_lsm(float* __restrict__ out) {
    long row = 32 + blockIdx.x;
    float* p = out + row * 32000L;
    float4* p4 = (float4*)p;
    int tid = threadIdx.x;
    __shared__ float sm[4];
    __shared__ float ss[4];
    float m = -1e30f;
    for (int i = tid; i < 8000; i += 256) {
        float4 v = p4[i];
        m = fmaxf(m, fmaxf(fmaxf(v.x, v.y), fmaxf(v.z, v.w)));
    }
    for (int off = 32; off; off >>= 1) m = fmaxf(m, __shfl_xor(m, off));
    if ((tid & 63) == 0) sm[tid >> 6] = m;
    __syncthreads();
    m = fmaxf(fmaxf(sm[0], sm[1]), fmaxf(sm[2], sm[3]));
    float s = 0;
    for (int i = tid; i < 8000; i += 256) {
        float4 v = p4[i];
        s += expf(v.x - m) + expf(v.y - m) + expf(v.z - m) + expf(v.w - m);
    }
    for (int off = 32; off; off >>= 1) s += __shfl_xor(s, off);
    if ((tid & 63) == 0) ss[tid >> 6] = s;
    __syncthreads();
    s = ss[0] + ss[1] + ss[2] + ss[3];
    float lse = m + logf(s);
    for (int i = tid; i < 8000; i += 256) {
        float4 v = p4[i];
        v.x -= lse; v.y -= lse; v.z -= lse; v.w -= lse;
        p4[i] = v;
    }
}

// ---------------- launch ----------------

extern "C" void kernel_launch(void* const* d_in, const int* in_sizes, int n_in,
                              void* d_out, int out_size, void* d_ws, size_t ws_size,
                              hipStream_t stream) {
    const float* eemb  = (const float*)d_in[0];
    const float* ewihf = (const float*)d_in[1];
    const float* ewhhf = (const float*)d_in[2];
    const float* ebf   = (const float*)d_in[3];
    const float* ewihb = (const float*)d_in[4];
    const float* ewhhb = (const float*)d_in[5];
    const float* ebb   = (const float*)d_in[6];
    const float* awi   = (const float*)d_in[7];
    const float* awo   = (const float*)d_in[8];
    const float* dwih  = (const float*)d_in[9];
    const float* dwhh  = (const float*)d_in[10];
    const float* db    = (const float*)d_in[11];
    const float* demb  = (const float*)d_in[12];
    const float* genw  = (const float*)d_in[13];
    const float* genb  = (const float*)d_in[14];
    const int* srci    = (const int*)d_in[15];
    const int* trgi    = (const int*)d_in[16];
    float* out = (float*)d_out;

    char* wsb = (char*)d_ws;
    float* F = (float*)d_ws;
    float* emb_src = F + 0L;              // 2048 x 300
    float* Xf      = F + 614400L;         // 2048 x 2048
    float* Xb      = F + 4808704L;        // 2048 x 2048
    float* enc_out = F + 9003008L;        // 64 x 32 x 1024
    float* h_enc0  = F + 11100160L;       // 2 x 32 x 512
    float* c_enc   = F + 11132928L;       // 2 x 32 x 512
    float* h_enc1  = F + 11165696L;       // 2 x 32 x 512
    float* trg_emb = F + 11198464L;       // 2016 x 300
    float* Xe      = F + 11803264L;       // 2016 x 4096
    float* h_dec0  = F + 20060800L;       // 32 x 1024
    float* h_dec1  = F + 20093568L;
    float* c_dec   = F + 20126336L;
    float* semi    = F + 20159104L;
    float* s_tilde = F + 20191872L;
    float* c_t     = F + 20224640L;
    unsigned short* genw_b = (unsigned short*)(wsb + 81029632ULL);  // 32000 x 1024 bf16
    unsigned short* HsB    = genw_b + 32768000ULL;                  // 2048 x 1024 bf16

    // init / precompute
    k_zero<<<2048, 256, 0, stream>>>(out, 1024000L);                         // t=0 rows
    k_zero<<<128, 256, 0, stream>>>(h_enc0, 32768L);
    k_zero<<<128, 256, 0, stream>>>(c_enc, 32768L);
    k_zero<<<64, 256, 0, stream>>>((float*)(HsB + 2016L * 1024), 16384L);    // pad rows
    k_gather<<<1024, 256, 0, stream>>>(eemb, srci, emb_src, 2048);
    k_gather<<<1024, 256, 0, stream>>>(demb, trgi, trg_emb, 2016);
    k_xw<<<dim3(32, 64), 256, 0, stream>>>(emb_src, ewihf, 300, 0, ebf, Xf, 2048);
    k_xw<<<dim3(32, 64), 256, 0, stream>>>(emb_src, ewihb, 300, 0, ebb, Xb, 2048);
    k_xw<<<dim3(64, 63), 256, 0, stream>>>(trg_emb, dwih, 1324, 1024, db, Xe, 4096);
    k_f2b<<<8192, 256, 0, stream>>>((const float4*)genw, (ushort4*)genw_b, 8192000L);

    // encoder recurrence (both directions per launch)
    for (int t = 0; t < 64; ++t) {
        const float* hin = (t & 1) ? h_enc1 : h_enc0;
        float* hout = (t & 1) ? h_enc0 : h_enc1;
        k_enc_step<<<128, 256, 0, stream>>>(Xf, Xb, ewhhf, ewhhb, hin, hout, c_enc, enc_out, t);
    }
    k_pack<<<128, 256, 0, stream>>>(h_enc0, c_enc, h_dec0, c_dec);

    // decoder recurrence
    for (int t = 0; t < 63; ++t) {
        const float* h = (t & 1) ? h_dec1 : h_dec0;
        float* hn = (t & 1) ? h_dec0 : h_dec1;
        k_semi<<<64, 256, 0, stream>>>(h, awi, semi);
        k_attn<<<32, 256, 0, stream>>>(enc_out, semi, s_tilde);
        k_ct<<<128, 256, 0, stream>>>(s_tilde, h, awo, c_t);
        k_dec_step<<<256, 256, 0, stream>>>(c_t, h, c_dec, Xe + (long)t * 32 * 4096,
                                            dwih, dwhh, hn, HsB + (long)t * 32 * 1024);
    }

    // batched generator + log-softmax
    k_gemm_gen<<<4000, 256, 0, stream>>>((const short*)HsB, (const short*)genw_b, genb, out);
    k_lsm<<<2016, 256, 0, stream>>>(out);
}

// Round 2
// 19791.066 us; speedup vs baseline: 1.2554x; 1.2554x over previous
//
#include <hip/hip_runtime.h>

typedef __attribute__((ext_vector_type(8))) short short8;
typedef __attribute__((ext_vector_type(4))) float f32x4;

#define NBLK 256

static __device__ __forceinline__ float sigf(float x) { return 1.0f / (1.0f + expf(-x)); }

static __device__ __forceinline__ unsigned short f2b(float f) {
    unsigned int u = __float_as_uint(f);
    u += 0x7FFFu + ((u >> 16) & 1u);   // round-to-nearest-even
    return (unsigned short)(u >> 16);
}

// device-scope grid barrier: single-use counter per barrier (no reset races).
static __device__ __forceinline__ void gbar(int* ctr) {
    __syncthreads();
    if (threadIdx.x == 0) {
        __threadfence();  // release: publish this block's writes device-wide
        __hip_atomic_fetch_add(ctr, 1, __ATOMIC_RELAXED, __HIP_MEMORY_SCOPE_AGENT);
        while (__hip_atomic_load(ctr, __ATOMIC_RELAXED, __HIP_MEMORY_SCOPE_AGENT) < NBLK)
            __builtin_amdgcn_s_sleep(1);
        __threadfence();  // acquire: invalidate stale cached lines
    }
    __syncthreads();
}

// ---------------- utility kernels ----------------

__global__ __launch_bounds__(256) void k_zero(float* __restrict__ p, long n) {
    for (long i = (long)blockIdx.x * 256 + threadIdx.x; i < n; i += (long)gridDim.x * 256) p[i] = 0.0f;
}

__global__ __launch_bounds__(256) void k_gather(const float* __restrict__ table,
                                                const int* __restrict__ idx,
                                                float* __restrict__ out, long nrows) {
    long total = nrows * 300;
    for (long i = (long)blockIdx.x * 256 + threadIdx.x; i < total; i += (long)gridDim.x * 256) {
        long r = i / 300;
        long d = i - r * 300;
        out[i] = table[(long)idx[r] * 300 + d];
    }
}

__global__ __launch_bounds__(256) void k_f2b(const float4* __restrict__ src,
                                             ushort4* __restrict__ dst, long n4) {
    for (long i = (long)blockIdx.x * 256 + threadIdx.x; i < n4; i += (long)gridDim.x * 256) {
        float4 v = src[i];
        ushort4 u;
        u.x = f2b(v.x); u.y = f2b(v.y); u.z = f2b(v.z); u.w = f2b(v.w);
        dst[i] = u;
    }
}

// out[m][j] = sum_{k<300} X[m][k] * W[j][wstride* + koff + k] + bias[j]
__global__ __launch_bounds__(256) void k_xw(const float* __restrict__ X,
                                            const float* __restrict__ W,
                                            int wstride, int koff,
                                            const float* __restrict__ bias,
                                            float* __restrict__ out, int N) {
    __shared__ float Xs[32][300];
    int m0 = blockIdx.y * 32;
    int j0 = blockIdx.x * 64;
    for (int i = threadIdx.x; i < 32 * 300; i += 256) {
        int r = i / 300, c = i - r * 300;
        Xs[r][c] = X[(long)(m0 + r) * 300 + c];
    }
    __syncthreads();
    int tx = threadIdx.x & 63, ty = threadIdx.x >> 6;
    int j = j0 + tx;
    const float* wr = W + (long)j * wstride + koff;
    float acc[8] = {0, 0, 0, 0, 0, 0, 0, 0};
    for (int k = 0; k < 300; ++k) {
        float w = wr[k];
#pragma unroll
        for (int mi = 0; mi < 8; ++mi) acc[mi] += Xs[ty * 8 + mi][k] * w;
    }
    float bv = bias[j];
#pragma unroll
    for (int mi = 0; mi < 8; ++mi)
        out[(long)(m0 + ty * 8 + mi) * N + j] = acc[mi] + bv;
}

// ---------------- persistent sequence kernel ----------------
// 256 blocks x 512 threads, all co-resident; software grid barriers between phases.
__global__ __launch_bounds__(512) void k_seq(
    const float* __restrict__ Xf, const float* __restrict__ Xb,
    const float* __restrict__ Xe,
    const float* __restrict__ whhf, const float* __restrict__ whhb,
    const float* __restrict__ awi, const float* __restrict__ awo,
    const float* __restrict__ dwih, const float* __restrict__ dwhh,
    float* __restrict__ enc_out,
    float* __restrict__ hbufE, float* __restrict__ c_enc,
    float* __restrict__ hdec, float* __restrict__ c_dec,
    float* __restrict__ semi, float* __restrict__ s_tilde, float* __restrict__ c_t,
    unsigned short* __restrict__ HsB, int* bars)
{
    __shared__ float red[512];
    __shared__ float sc[64];
    __shared__ float ex[128][4];

    const int tid = threadIdx.x;
    const int bid = blockIdx.x;
    const int gt = bid * 512 + tid;
    int bi = 0;

    // P0: zero initial state + HsB pad rows
    if (gt < 32768) hbufE[gt] = 0.0f;
    else if (gt < 65536) c_enc[gt - 32768] = 0.0f;
    else if (gt < 81920) ((float*)(HsB + 2016 * 1024))[gt - 65536] = 0.0f;
    gbar(bars + bi++);

    const int jl = tid & 15;          // 16 consecutive j per wave -> 16-row weight loads
    const int bq = (tid >> 4) & 7;    // 8 b per block
    const int q  = tid >> 7;          // gate / K-quarter split
    const int l  = tid & 127;         // exchange slot

    // ---------------- encoder: 64 steps, 1 barrier each ----------------
    {
        const int jpart = bid & 31;
        const int grp2 = bid >> 5;
        const int dir = grp2 >> 2;
        const int b = ((grp2 & 3) << 3) + bq;
        const int j = (jpart << 4) + jl;
        const float* whh = dir ? whhb : whhf;
        const float* X = dir ? Xb : Xf;
        const int row = (q << 9) + j;                       // gate q, output j
        const float4* w4 = (const float4*)(whh + (size_t)row * 512);
        const int hoff = ((dir << 5) + b) * 512;
        for (int t = 0; t < 64; ++t) {
            const float* hin = hbufE + ((t & 1) ? 32768 : 0);
            float* hout = hbufE + ((t & 1) ? 0 : 32768);
            const int s = dir ? (63 - t) : t;
            const float4* h4 = (const float4*)(hin + hoff);
            float a0 = 0, a1 = 0, a2 = 0, a3 = 0;
#pragma unroll 4
            for (int k = 0; k < 128; ++k) {
                float4 hh = h4[k], w = w4[k];
                a0 += hh.x * w.x; a1 += hh.y * w.y; a2 += hh.z * w.z; a3 += hh.w * w.w;
            }
            float a = (a0 + a1) + (a2 + a3);
            a += X[(size_t)(s * 32 + b) * 2048 + row];
            ex[l][q] = a;
            __syncthreads();
            if (q == 0) {
                float gi = ex[l][0], gf = ex[l][1], gg = ex[l][2], go = ex[l][3];
                int hi = hoff + j;
                float cv = c_enc[hi];
                float c2 = sigf(gf) * cv + sigf(gi) * tanhf(gg);
                float h2 = sigf(go) * tanhf(c2);
                c_enc[hi] = c2;
                hout[hi] = h2;
                enc_out[(size_t)(s * 32 + b) * 1024 + (dir << 9) + j] = h2;
            }
            gbar(bars + bi++);
        }
    }

    // pack encoder finals into decoder h,c:  hdec[b][2k+d] = h_final[d][b][k]
    if (gt < 32768) {
        int b = gt >> 10, jj = gt & 1023, kk = jj >> 1, d = jj & 1;
        hdec[gt] = hbufE[((d << 5) + b) * 512 + kk];
    } else if (gt < 65536) {
        int i = gt - 32768;
        int b = i >> 10, jj = i & 1023, kk = jj >> 1, d = jj & 1;
        c_dec[i] = c_enc[((d << 5) + b) * 512 + kk];
    }
    gbar(bars + bi++);

    // ---------------- decoder: 63 steps, 4 barriers each ----------------
    const int jpart = bid & 63;
    const int b = ((bid >> 6) << 3) + bq;
    const int j = (jpart << 4) + jl;
    for (int t = 0; t < 63; ++t) {
        const float* h = hdec + ((t & 1) ? 32768 : 0);
        float* hn = hdec + ((t & 1) ? 0 : 32768);

        // P1: semi[b][j] = h[b] . awi[j]   (K split 4x256)
        {
            const float4* h4 = (const float4*)(h + b * 1024) + (q << 6);
            const float4* w4 = (const float4*)(awi + (size_t)j * 1024) + (q << 6);
            float a0 = 0, a1 = 0, a2 = 0, a3 = 0;
#pragma unroll 4
            for (int k = 0; k < 64; ++k) {
                float4 x = h4[k], w = w4[k];
                a0 += x.x * w.x; a1 += x.y * w.y; a2 += x.z * w.z; a3 += x.w * w.w;
            }
            ex[l][q] = (a0 + a1) + (a2 + a3);
            __syncthreads();
            if (q == 0) semi[b * 1024 + j] = ex[l][0] + ex[l][1] + ex[l][2] + ex[l][3];
        }
        gbar(bars + bi++);

        // P2: attention -> s_tilde (blocks 0..31, one per batch item)
        if (bid < 32) {
            int bb = bid;
            int s = tid >> 3, part = tid & 7;
            const float4* er = (const float4*)(enc_out + ((size_t)s * 32 + bb) * 1024) + part * 32;
            const float4* sr = (const float4*)(semi + bb * 1024) + part * 32;
            float acc = 0;
            for (int k = 0; k < 32; ++k) {
                float4 e = er[k], m = sr[k];
                acc += e.x * m.x + e.y * m.y + e.z * m.z + e.w * m.w;
            }
            red[tid] = acc;
            __syncthreads();
            if (tid < 64) {
                float v = 0;
#pragma unroll
                for (int p = 0; p < 8; ++p) v += red[tid * 8 + p];
                float m = v;
                for (int off = 32; off; off >>= 1) m = fmaxf(m, __shfl_xor(m, off));
                float e = expf(v - m);
                float sum = e;
                for (int off = 32; off; off >>= 1) sum += __shfl_xor(sum, off);
                sc[tid] = e / sum;
            }
            __syncthreads();
            int j0 = tid * 2;
            float st0 = 0, st1 = 0;
            for (int s2 = 0; s2 < 64; ++s2) {
                float p = sc[s2];
                float2 e = *(const float2*)(enc_out + ((size_t)s2 * 32 + bb) * 1024 + j0);
                st0 += p * e.x; st1 += p * e.y;
            }
            *(float2*)(s_tilde + bb * 1024 + j0) = make_float2(st0, st1);
        }
        gbar(bars + bi++);

        // P3: c_t[b][j] = tanh([s_tilde,h][b] . awo[j])  (K split 4x512)
        {
            const float* srcp = (q < 2 ? s_tilde : h) + b * 1024 + ((q & 1) << 9);
            const float4* s4 = (const float4*)srcp;
            const float4* w4 = (const float4*)(awo + (size_t)j * 2048 + (q << 9));
            float a0 = 0, a1 = 0, a2 = 0, a3 = 0;
#pragma unroll 4
            for (int k = 0; k < 128; ++k) {
                float4 x = s4[k], w = w4[k];
                a0 += x.x * w.x; a1 += x.y * w.y; a2 += x.z * w.z; a3 += x.w * w.w;
            }
            ex[l][q] = (a0 + a1) + (a2 + a3);
            __syncthreads();
            if (q == 0) c_t[b * 1024 + j] = tanhf(ex[l][0] + ex[l][1] + ex[l][2] + ex[l][3]);
        }
        gbar(bars + bi++);

        // P4: gates (gate q over K=2048) + cell + bf16 h for generator
        {
            size_t jg = (size_t)q * 1024 + j;
            const float4* ct4 = (const float4*)(c_t + b * 1024);
            const float4* h4 = (const float4*)(h + b * 1024);
            const float4* wi4 = (const float4*)(dwih + jg * 1324);
            const float4* wh4 = (const float4*)(dwhh + jg * 1024);
            float a0 = 0, a1 = 0, a2 = 0, a3 = 0, c0 = 0, c1 = 0, c2s = 0, c3 = 0;
#pragma unroll 2
            for (int k = 0; k < 256; ++k) {
                float4 x = ct4[k], w = wi4[k];
                a0 += x.x * w.x; a1 += x.y * w.y; a2 += x.z * w.z; a3 += x.w * w.w;
                float4 y = h4[k], v = wh4[k];
                c0 += y.x * v.x; c1 += y.y * v.y; c2s += y.z * v.z; c3 += y.w * v.w;
            }
            float a = ((a0 + a1) + (a2 + a3)) + ((c0 + c1) + (c2s + c3));
            a += Xe[((size_t)t * 32 + b) * 4096 + (q << 10) + j];
            ex[l][q] = a;
            __syncthreads();
            if (q == 0) {
                float gi = ex[l][0], gf = ex[l][1], gg = ex[l][2], go = ex[l][3];
                int hi = b * 1024 + j;
                float cv = c_dec[hi];
                float c2 = sigf(gf) * cv + sigf(gi) * tanhf(gg);
                float h2 = sigf(go) * tanhf(c2);
                c_dec[hi] = c2;
                hn[hi] = h2;
                HsB[((size_t)t * 32 + b) * 1024 + j] = f2b(h2);
            }
        }
        gbar(bars + bi++);
    }
}

// ---------------- generator GEMM (bf16 MFMA) ----------------
__global__ __launch_bounds__(256) void k_gemm_gen(const short* __restrict__ A,
                                                  const short* __restrict__ B,
                                                  const float* __restrict__ genb,
                                                  float* __restrict__ out) {
    int wave = threadIdx.x >> 6;
    int lane = threadIdx.x & 63;
    int tile = blockIdx.x * 4 + wave;  // 16000 tiles = 32 m x 500 n
    int mt = tile & 31;
    int nt = tile >> 5;
    int m0 = mt * 64, n0 = nt * 64;
    int lr = lane & 15;
    int lk = (lane >> 4) * 8;
    f32x4 acc[4][4] = {};
    for (int k0 = 0; k0 < 1024; k0 += 32) {
        short8 a[4], bfr[4];
#pragma unroll
        for (int mi = 0; mi < 4; ++mi)
            a[mi] = *(const short8*)(A + (long)(m0 + mi * 16 + lr) * 1024 + k0 + lk);
#pragma unroll
        for (int ni = 0; ni < 4; ++ni)
            bfr[ni] = *(const short8*)(B + (long)(n0 + ni * 16 + lr) * 1024 + k0 + lk);
#pragma unroll
        for (int mi = 0; mi < 4; ++mi)
#pragma unroll
            for (int ni = 0; ni < 4; ++ni)
                acc[mi][ni] = __builtin_amdgcn_mfma_f32_16x16x32_bf16(a[mi], bfr[ni], acc[mi][ni], 0, 0, 0);
    }
    int dcol = lane & 15;
    int drow = (lane >> 4) * 4;
#pragma unroll
    for (int mi = 0; mi < 4; ++mi) {
        int mbase = m0 + mi * 16 + drow;
#pragma unroll
        for (int ni = 0; ni < 4; ++ni) {
            int n = n0 + ni * 16 + dcol;
            float bv = genb[n];
            f32x4 v = acc[mi][ni];
#pragma unroll
            for (int r = 0; r < 4; ++r) {
                int m = mbase + r;
                if (m < 2016) out[(long)(m + 32) * 32000 + n] = v[r] + bv;
            }
        }
    }
}

// in-place log-softmax on d_out rows 32..2047
__global__ __launch_bounds__(256) void k_lsm(float* __restrict__ out) {
    long row = 32 + blockIdx.x;
    float* p = out + row * 32000L;
    float4* p4 = (float4*)p;
    int tid = threadIdx.x;
    __shared__ float sm[4];
    __shared__ float ss[4];
    float m = -1e30f;
    for (int i = tid; i < 8000; i += 256) {
        float4 v = p4[i];
        m = fmaxf(m, fmaxf(fmaxf(v.x, v.y), fmaxf(v.z, v.w)));
    }
    for (int off = 32; off; off >>= 1) m = fmaxf(m, __shfl_xor(m, off));
    if ((tid & 63) == 0) sm[tid >> 6] = m;
    __syncthreads();
    m = fmaxf(fmaxf(sm[0], sm[1]), fmaxf(sm[2], sm[3]));
    float s = 0;
    for (int i = tid; i < 8000; i += 256) {
        float4 v = p4[i];
        s += expf(v.x - m) + expf(v.y - m) + expf(v.z - m) + expf(v.w - m);
    }
    for (int off = 32; off; off >>= 1) s += __shfl_xor(s, off);
    if ((tid & 63) == 0) ss[tid >> 6] = s;
    __syncthreads();
    s = ss[0] + ss[1] + ss[2] + ss[3];
    float lse = m + logf(s);
    for (int i = tid; i < 8000; i += 256) {
        float4 v = p4[i];
        v.x -= lse; v.y -= lse; v.z -= lse; v.w -= lse;
        p4[i] = v;
    }
}

// ---------------- launch ----------------

extern "C" void kernel_launch(void* const* d_in, const int* in_sizes, int n_in,
                              void* d_out, int out_size, void* d_ws, size_t ws_size,
                              hipStream_t stream) {
    const float* eemb  = (const float*)d_in[0];
    const float* ewihf = (const float*)d_in[1];
    const float* ewhhf = (const float*)d_in[2];
    const float* ebf   = (const float*)d_in[3];
    const float* ewihb = (const float*)d_in[4];
    const float* ewhhb = (const float*)d_in[5];
    const float* ebb   = (const float*)d_in[6];
    const float* awi   = (const float*)d_in[7];
    const float* awo   = (const float*)d_in[8];
    const float* dwih  = (const float*)d_in[9];
    const float* dwhh  = (const float*)d_in[10];
    const float* db    = (const float*)d_in[11];
    const float* demb  = (const float*)d_in[12];
    const float* genw  = (const float*)d_in[13];
    const float* genb  = (const float*)d_in[14];
    const int* srci    = (const int*)d_in[15];
    const int* trgi    = (const int*)d_in[16];
    float* out = (float*)d_out;

    char* wsb = (char*)d_ws;
    float* F = (float*)d_ws;
    int*   bars    = (int*)F;             // 2048 ints, overlaps emb_src (zeroed after k_xw reads)
    float* emb_src = F + 0L;              // 2048 x 300
    float* Xf      = F + 614400L;         // 2048 x 2048
    float* Xb      = F + 4808704L;        // 2048 x 2048
    float* enc_out = F + 9003008L;        // 64 x 32 x 1024
    float* trg_emb = F + 11100160L;       // 2016 x 300
    float* Xe      = F + 11704960L;       // 2016 x 4096
    float* hbufE   = F + 19962496L;       // 2 x (2 x 32 x 512)
    float* c_enc   = F + 20028032L;       // 2 x 32 x 512
    float* h_dec   = F + 20060800L;       // 2 x (32 x 1024)
    float* c_dec   = F + 20126336L;
    float* semi    = F + 20159104L;
    float* s_tilde = F + 20191872L;
    float* c_t     = F + 20224640L;
    unsigned short* genw_b = (unsigned short*)(wsb + 81029632ULL);  // 32000 x 1024 bf16
    unsigned short* HsB    = genw_b + 32768000ULL;                  // 2048 x 1024 bf16

    // precompute (parallel, launch-order dependencies only)
    k_gather<<<1024, 256, 0, stream>>>(eemb, srci, emb_src, 2048);
    k_gather<<<1024, 256, 0, stream>>>(demb, trgi, trg_emb, 2016);
    k_xw<<<dim3(32, 64), 256, 0, stream>>>(emb_src, ewihf, 300, 0, ebf, Xf, 2048);
    k_xw<<<dim3(32, 64), 256, 0, stream>>>(emb_src, ewihb, 300, 0, ebb, Xb, 2048);
    k_xw<<<dim3(64, 63), 256, 0, stream>>>(trg_emb, dwih, 1324, 1024, db, Xe, 4096);
    k_f2b<<<8192, 256, 0, stream>>>((const float4*)genw, (ushort4*)genw_b, 8192000L);
    k_zero<<<2048, 256, 0, stream>>>(out, 1024000L);   // t=0 output rows
    k_zero<<<8, 256, 0, stream>>>(F, 2048L);           // barrier counters (after k_xw read emb_src)

    // persistent recurrence kernel: encoder + decoder, grid barriers inside
    k_seq<<<NBLK, 512, 0, stream>>>(Xf, Xb, Xe, ewhhf, ewhhb, awi, awo, dwih, dwhh,
                                    enc_out, hbufE, c_enc, h_dec, c_dec,
                                    semi, s_tilde, c_t, HsB, bars);

    // batched generator + log-softmax
    k_gemm_gen<<<4000, 256, 0, stream>>>((const short*)HsB, (const short*)genw_b, genb, out);
    k_lsm<<<2016, 256, 0, stream>>>(out);
}

// Round 3
// 5436.214 us; speedup vs baseline: 4.5705x; 3.6406x over previous
//
#include <hip/hip_runtime.h>

typedef __attribute__((ext_vector_type(8))) short short8;
typedef __attribute__((ext_vector_type(4))) float f32x4;
typedef unsigned short u16;
typedef unsigned int u32;

#define NBLK 64

static __device__ __forceinline__ float sigf(float x){ return 1.0f/(1.0f+expf(-x)); }

static __device__ __forceinline__ u16 f2b(float f){
    u32 u = __float_as_uint(f);
    u += 0x7FFFu + ((u>>16)&1u);   // RNE
    return (u16)(u>>16);
}
static __device__ __forceinline__ float us2f(u16 s){ return __uint_as_float(((u32)s)<<16); }
static __device__ __forceinline__ float b2f_lo(u32 u){ return __uint_as_float(u<<16); }
static __device__ __forceinline__ float b2f_hi(u32 u){ return __uint_as_float(u & 0xffff0000u); }

// Grid barrier WITHOUT cache invalidation:
//  - writeback dirty L2 lines (clean lines stay resident -> weights survive)
//  - single-use relaxed agent-scope counter
//  - correctness relies on fresh-address discipline for all cross-block data
static __device__ __forceinline__ void gbar(int* ctr) {
    __syncthreads();   // compiler drains vmcnt/lgkmcnt before s_barrier
    if (threadIdx.x == 0) {
        asm volatile("buffer_wbl2 sc1\n\ts_waitcnt vmcnt(0)" ::: "memory");
        __hip_atomic_fetch_add(ctr, 1, __ATOMIC_RELAXED, __HIP_MEMORY_SCOPE_AGENT);
        while (__hip_atomic_load(ctr, __ATOMIC_RELAXED, __HIP_MEMORY_SCOPE_AGENT) < NBLK)
            __builtin_amdgcn_s_sleep(1);
        asm volatile("" ::: "memory");
    }
    __syncthreads();
}

// ---------------- utility / conversion kernels ----------------

__global__ __launch_bounds__(256) void k_zero(float* __restrict__ p, long n) {
    for (long i = (long)blockIdx.x*256 + threadIdx.x; i < n; i += (long)gridDim.x*256) p[i] = 0.0f;
}

__global__ __launch_bounds__(256) void k_f2b(const float4* __restrict__ src,
                                             ushort4* __restrict__ dst, long n4) {
    for (long i = (long)blockIdx.x*256 + threadIdx.x; i < n4; i += (long)gridDim.x*256) {
        float4 v = src[i];
        ushort4 u;
        u.x = f2b(v.x); u.y = f2b(v.y); u.z = f2b(v.z); u.w = f2b(v.w);
        dst[i] = u;
    }
}

// WencB[(j*4+q)*512 + k] = bf16(whh[(q*512+j)*512 + k])
__global__ __launch_bounds__(256) void k_wenc(const float* __restrict__ whh, u16* __restrict__ dst) {
    int i = blockIdx.x*256 + threadIdx.x;           // 1,048,576
    int n = i >> 9, k = i & 511;
    int j = n >> 2, q = n & 3;
    dst[i] = f2b(whh[(size_t)(q*512 + j)*512 + k]);
}

// awiTB[kcol*1024 + n] = bf16(awi[n*1024 + kcol])
__global__ __launch_bounds__(256) void k_awiT(const float* __restrict__ awi, u16* __restrict__ dst) {
    int i = blockIdx.x*256 + threadIdx.x;           // 1,048,576
    int kcol = i >> 10, n = i & 1023;
    dst[i] = f2b(awi[(size_t)n*1024 + kcol]);
}

// WdecB[(j*4+q)*2048 + k] = bf16( k<1024 ? dwih[(q*1024+j)*1324+k] : dwhh[(q*1024+j)*1024+k-1024] )
__global__ __launch_bounds__(256) void k_wdec(const float* __restrict__ dwih,
                                              const float* __restrict__ dwhh,
                                              u16* __restrict__ dst) {
    for (long i = (long)blockIdx.x*256 + threadIdx.x; i < 8388608L; i += (long)gridDim.x*256) {
        int n = (int)(i >> 11), k = (int)(i & 2047);
        int j = n >> 2, q = n & 3;
        float v = (k < 1024) ? dwih[(size_t)(q*1024 + j)*1324 + k]
                             : dwhh[(size_t)(q*1024 + j)*1024 + (k - 1024)];
        dst[i] = f2b(v);
    }
}

// X = gather(table, idx) @ W[:, koff:koff+300]^T + bias, stored bf16, gate-packed col = (jj&jmask)*4 | (jj>>jshift)
__global__ __launch_bounds__(256) void k_xw(const float* __restrict__ table,
                                            const int* __restrict__ idx,
                                            const float* __restrict__ W,
                                            int wstride, int koff,
                                            const float* __restrict__ bias,
                                            u16* __restrict__ outU, int N,
                                            int jmask, int jshift) {
    __shared__ float Xs[32][300];
    int m0 = blockIdx.y * 32;
    int j0 = blockIdx.x * 64;
    for (int i = threadIdx.x; i < 32*300; i += 256) {
        int r = i/300, c = i - r*300;
        Xs[r][c] = table[(size_t)idx[m0+r]*300 + c];
    }
    __syncthreads();
    int tx = threadIdx.x & 63, ty = threadIdx.x >> 6;
    int jj = j0 + tx;
    const float* wr = W + (size_t)jj*wstride + koff;
    float acc[8] = {0,0,0,0,0,0,0,0};
    for (int k = 0; k < 300; ++k) {
        float w = wr[k];
#pragma unroll
        for (int mi = 0; mi < 8; ++mi) acc[mi] += Xs[ty*8+mi][k] * w;
    }
    float bv = bias[jj];
    int col = ((jj & jmask) << 2) | (jj >> jshift);
#pragma unroll
    for (int mi = 0; mi < 8; ++mi)
        outU[(size_t)(m0 + ty*8 + mi)*N + col] = f2b(acc[mi] + bv);
}

// ---------------- persistent recurrence kernel ----------------
// 64 blocks x 512 threads (8 waves). All matmuls via MFMA in bf16.
// Fresh-address discipline: every cross-block datum has a unique per-step slot.
__global__ __launch_bounds__(512) void k_seq(
    const u16* __restrict__ Xf, const u16* __restrict__ Xb, const u16* __restrict__ Xe,
    const u16* __restrict__ WencB, const u16* __restrict__ awiTB,
    const u16* __restrict__ awoB, const u16* __restrict__ WdecB,
    u16* __restrict__ encBX,   // 65 slots [32][1024]: slot 0 zeros, slot s+1 = enc_out[s] (bf16)
    u16* __restrict__ Hd,      // 65 slots [32][1024]: slot 0 init hidden, slot t+1 = h after dec step t, slot 64 zeros
    u16* __restrict__ Stb,     // 63 slots [32][1024] s_tilde
    u16* __restrict__ Ctb,     // 63 slots [32][1024] c_t
    u16* __restrict__ encPB,   // [2048][1024] enc_out @ attn_wi (bf16)
    float* __restrict__ cfin,  // [2][32][512] final encoder c
    int* bars)
{
    __shared__ float SH[2304];
    const int tid = threadIdx.x;
    const int bid = blockIdx.x;
    const int wv = tid >> 6, lane = tid & 63;
    const int gwave = bid*8 + wv;
    const int lr = lane & 15, lk8 = (lane >> 4)*8;
    const int b_l = lane & 15, jjq = lane >> 4;
    const int gt = bid*512 + tid;
    int bi = 0;

    // ---- P0: zero encBX slot 0 ----
    if (gt < 16384) ((u32*)encBX)[gt] = 0u;
    gbar(bars + bi++);

    // ---- encoder: 64 steps ----
    {
        const int dir = gwave >> 8;
        const int mt = (gwave >> 7) & 1;
        const int nt = gwave & 127;
        const int m0 = mt*16, n0 = nt*16;
        const u16* Bw = WencB + (size_t)dir*1048576 + (size_t)(n0+lr)*512 + lk8;
        const u16* Xd = dir ? Xb : Xf;
        float* T = SH + wv*272;
        const int bb = m0 + b_l;
        const int j = nt*4 + jjq;
        float creg = 0.f;
        for (int t = 0; t < 64; ++t) {
            const int rslot = (t==0) ? 0 : (dir ? (65-t) : t);
            const u16* Ah = encBX + (size_t)rslot*32768 + (size_t)(m0+lr)*1024 + dir*512 + lk8;
            f32x4 acc = {0.f,0.f,0.f,0.f};
#pragma unroll
            for (int i = 0; i < 16; ++i) {
                short8 av = *(const short8*)(Ah + i*32);
                short8 bv = *(const short8*)(Bw + i*32);
                acc = __builtin_amdgcn_mfma_f32_16x16x32_bf16(av, bv, acc, 0, 0, 0);
            }
            {
                const int rb = (lane>>4)*4;
#pragma unroll
                for (int r = 0; r < 4; ++r) T[(rb+r)*17 + (lane&15)] = acc[r];
            }
            __builtin_amdgcn_sched_barrier(0);
            const int s = dir ? (63-t) : t;
            ushort4 xr = *(const ushort4*)(Xd + (size_t)(s*32+bb)*2048 + n0 + jjq*4);
            float gi = T[b_l*17 + jjq*4 + 0] + us2f(xr.x);
            float gf = T[b_l*17 + jjq*4 + 1] + us2f(xr.y);
            float gg = T[b_l*17 + jjq*4 + 2] + us2f(xr.z);
            float go = T[b_l*17 + jjq*4 + 3] + us2f(xr.w);
            float c2 = sigf(gf)*creg + sigf(gi)*tanhf(gg);
            float h2 = sigf(go)*tanhf(c2);
            creg = c2;
            encBX[(size_t)(s+1)*32768 + (size_t)bb*1024 + dir*512 + j] = f2b(h2);
            gbar(bars + bi++);
        }
        cfin[dir*16384 + bb*512 + j] = creg;
    }

    // ---- pack: Hd[0] = interleaved final h; zero Hd[64] (generator pad) ----
    {
        int b = gt >> 10, jj2 = gt & 1023;
        int d = jj2 & 1, k = jj2 >> 1;
        Hd[(size_t)b*1024 + jj2] = encBX[(size_t)(d ? 1 : 64)*32768 + (size_t)b*1024 + d*512 + k];
        Hd[(size_t)64*32768 + gt] = 0;
    }
    gbar(bars + bi++);

    // ---- encP = enc_out @ attn_wi  (M=2048, N=1024, K=1024) ----
    {
        const u16* Abase = encBX + 32768;
        for (int ii = 0; ii < 16; ++ii) {
            int id = gwave*16 + ii;
            int mt2 = id >> 6, nt2 = id & 63;
            int m0 = mt2*16, n0 = nt2*16;
            const u16* Ar = Abase + (size_t)(m0+lr)*1024 + lk8;
            const u16* Br = awiTB + (size_t)(n0+lr)*1024 + lk8;
            f32x4 acc = {0.f,0.f,0.f,0.f};
#pragma unroll 8
            for (int i = 0; i < 32; ++i) {
                short8 av = *(const short8*)(Ar + i*32);
                short8 bv = *(const short8*)(Br + i*32);
                acc = __builtin_amdgcn_mfma_f32_16x16x32_bf16(av, bv, acc, 0, 0, 0);
            }
            int col = n0 + (lane&15);
            int rb = m0 + (lane>>4)*4;
#pragma unroll
            for (int r = 0; r < 4; ++r)
                encPB[(size_t)(rb+r)*1024 + col] = f2b(acc[r]);
        }
    }
    gbar(bars + bi++);

    // ---- decoder: c-init from cfin (c lives in registers) ----
    const int nt4 = gwave >> 1, mt4 = gwave & 1;
    const int n0d = nt4*16, m0d = mt4*16;
    const int bbd = m0d + b_l;
    const int jd = nt4*4 + jjq;
    float cdec = cfin[(jd&1)*16384 + bbd*512 + (jd>>1)];

    // ---- decoder: 63 steps x {P2 attn, P3 c_t, P4 gates+cell} ----
    for (int t = 0; t < 63; ++t) {
        // P2: scores = encP . h ; softmax(S=64); s_tilde = sum_s p_s * enc_out[s]
        if (bid < 32) {
            const int bbb = bid;
            float* hsh = SH; float* red = SH + 1024; float* sc = SH + 1536;
            {
                u32 u = ((const u32*)Hd)[(size_t)t*16384 + bbb*512 + tid];
                hsh[2*tid]   = b2f_lo(u);
                hsh[2*tid+1] = b2f_hi(u);
            }
            __syncthreads();
            {
                int s = tid >> 3, p = tid & 7;
                const uint4* ep = (const uint4*)(encPB + (size_t)(s*32+bbb)*1024 + p*128);
                const float* hk = hsh + p*128;
                float a0=0,a1=0,a2=0,a3=0;
#pragma unroll 4
                for (int q8 = 0; q8 < 16; ++q8) {
                    uint4 u = ep[q8];
                    a0 += b2f_lo(u.x)*hk[q8*8+0] + b2f_hi(u.x)*hk[q8*8+1];
                    a1 += b2f_lo(u.y)*hk[q8*8+2] + b2f_hi(u.y)*hk[q8*8+3];
                    a2 += b2f_lo(u.z)*hk[q8*8+4] + b2f_hi(u.z)*hk[q8*8+5];
                    a3 += b2f_lo(u.w)*hk[q8*8+6] + b2f_hi(u.w)*hk[q8*8+7];
                }
                red[tid] = (a0+a1)+(a2+a3);
            }
            __syncthreads();
            if (tid < 64) {
                float v = 0;
#pragma unroll
                for (int pp = 0; pp < 8; ++pp) v += red[tid*8+pp];
                float m = v;
                for (int off = 32; off; off >>= 1) m = fmaxf(m, __shfl_xor(m, off));
                float e = expf(v - m);
                float ss = e;
                for (int off = 32; off; off >>= 1) ss += __shfl_xor(ss, off);
                sc[tid] = e / ss;
            }
            __syncthreads();
            {
                float st0 = 0, st1 = 0;
                const u32* eb = (const u32*)encBX + 16384 + bbb*512 + tid;  // slot s2+1
#pragma unroll 4
                for (int s2 = 0; s2 < 64; ++s2) {
                    u32 u = eb[(size_t)s2*16384];
                    float w = sc[s2];
                    st0 += w*b2f_lo(u); st1 += w*b2f_hi(u);
                }
                u32 pk = (u32)f2b(st0) | ((u32)f2b(st1) << 16);
                ((u32*)Stb)[(size_t)t*16384 + bbb*512 + tid] = pk;
            }
        }
        gbar(bars + bi++);

        // P3: c_t = tanh([s_tilde, h] @ awo^T)  (K split 4 ways across waves)
        {
            const int nt3 = bid;
            const int mt3 = wv >> 2, kq = wv & 3;
            const int m0 = mt3*16, n0 = nt3*16;
            const u16* Br = awoB + (size_t)(n0+lr)*2048 + kq*512 + lk8;
            const u16* As  = Stb + (size_t)t*32768 + (size_t)(m0+lr)*1024 + kq*512 + lk8;
            const u16* Ah2 = Hd  + (size_t)t*32768 + (size_t)(m0+lr)*1024 + (kq-2)*512 + lk8;
            const u16* Ar = (kq < 2) ? As : Ah2;
            f32x4 acc = {0.f,0.f,0.f,0.f};
#pragma unroll 4
            for (int i = 0; i < 16; ++i) {
                short8 av = *(const short8*)(Ar + i*32);
                short8 bv = *(const short8*)(Br + i*32);
                acc = __builtin_amdgcn_mfma_f32_16x16x32_bf16(av, bv, acc, 0, 0, 0);
            }
            float* PH = SH + wv*256;
#pragma unroll
            for (int r = 0; r < 4; ++r) PH[lane*4 + r] = acc[r];
            __syncthreads();
            if (kq == 0) {
#pragma unroll
                for (int r = 0; r < 4; ++r) {
                    float sum = SH[wv*256 + lane*4 + r] + SH[(wv+1)*256 + lane*4 + r]
                              + SH[(wv+2)*256 + lane*4 + r] + SH[(wv+3)*256 + lane*4 + r];
                    int bq = m0 + (lane>>4)*4 + r;
                    Ctb[(size_t)t*32768 + (size_t)bq*1024 + n0 + (lane&15)] = f2b(tanhf(sum));
                }
            }
        }
        gbar(bars + bi++);

        // P4: gates = [c_t, h] @ Wdec^T + Xe ; cell update; h -> Hd[t+1]
        {
            const u16* Br  = WdecB + (size_t)(n0d+lr)*2048 + lk8;
            const u16* Ac  = Ctb + (size_t)t*32768 + (size_t)(m0d+lr)*1024 + lk8;
            const u16* Ah3 = Hd  + (size_t)t*32768 + (size_t)(m0d+lr)*1024 + lk8;
            f32x4 acc = {0.f,0.f,0.f,0.f};
#pragma unroll 4
            for (int i = 0; i < 32; ++i) {
                short8 av = *(const short8*)(Ac + i*32);
                short8 bv = *(const short8*)(Br + i*32);
                acc = __builtin_amdgcn_mfma_f32_16x16x32_bf16(av, bv, acc, 0, 0, 0);
            }
#pragma unroll 4
            for (int i = 0; i < 32; ++i) {
                short8 av = *(const short8*)(Ah3 + i*32);
                short8 bv = *(const short8*)(Br + 1024 + i*32);
                acc = __builtin_amdgcn_mfma_f32_16x16x32_bf16(av, bv, acc, 0, 0, 0);
            }
            float* T = SH + wv*272;
            {
                const int rb = (lane>>4)*4;
#pragma unroll
                for (int r = 0; r < 4; ++r) T[(rb+r)*17 + (lane&15)] = acc[r];
            }
            __builtin_amdgcn_sched_barrier(0);
            ushort4 xr = *(const ushort4*)(Xe + (size_t)(t*32+bbd)*4096 + n0d + jjq*4);
            float gi = T[b_l*17 + jjq*4 + 0] + us2f(xr.x);
            float gf = T[b_l*17 + jjq*4 + 1] + us2f(xr.y);
            float gg = T[b_l*17 + jjq*4 + 2] + us2f(xr.z);
            float go = T[b_l*17 + jjq*4 + 3] + us2f(xr.w);
            float c2 = sigf(gf)*cdec + sigf(gi)*tanhf(gg);
            float h2 = sigf(go)*tanhf(c2);
            cdec = c2;
            Hd[(size_t)(t+1)*32768 + (size_t)bbd*1024 + jd] = f2b(h2);
        }
        gbar(bars + bi++);
    }
}

// ---------------- generator GEMM (bf16 MFMA) ----------------
__global__ __launch_bounds__(256) void k_gemm_gen(const short* __restrict__ A,
                                                  const short* __restrict__ B,
                                                  const float* __restrict__ genb,
                                                  float* __restrict__ out) {
    int wave = threadIdx.x >> 6;
    int lane = threadIdx.x & 63;
    int tile = blockIdx.x * 4 + wave;  // 16000 tiles = 32 m x 500 n
    int mt = tile & 31;
    int nt = tile >> 5;
    int m0 = mt*64, n0 = nt*64;
    int lr = lane & 15;
    int lk = (lane >> 4)*8;
    f32x4 acc[4][4] = {};
    for (int k0 = 0; k0 < 1024; k0 += 32) {
        short8 a[4], bfr[4];
#pragma unroll
        for (int mi = 0; mi < 4; ++mi)
            a[mi] = *(const short8*)(A + (long)(m0 + mi*16 + lr)*1024 + k0 + lk);
#pragma unroll
        for (int ni = 0; ni < 4; ++ni)
            bfr[ni] = *(const short8*)(B + (long)(n0 + ni*16 + lr)*1024 + k0 + lk);
#pragma unroll
        for (int mi = 0; mi < 4; ++mi)
#pragma unroll
            for (int ni = 0; ni < 4; ++ni)
                acc[mi][ni] = __builtin_amdgcn_mfma_f32_16x16x32_bf16(a[mi], bfr[ni], acc[mi][ni], 0, 0, 0);
    }
    int dcol = lane & 15;
    int drow = (lane >> 4)*4;
#pragma unroll
    for (int mi = 0; mi < 4; ++mi) {
        int mbase = m0 + mi*16 + drow;
#pragma unroll
        for (int ni = 0; ni < 4; ++ni) {
            int n = n0 + ni*16 + dcol;
            float bv = genb[n];
            f32x4 v = acc[mi][ni];
#pragma unroll
            for (int r = 0; r < 4; ++r) {
                int m = mbase + r;
                if (m < 2016) out[(long)(m + 32)*32000 + n] = v[r] + bv;
            }
        }
    }
}

// in-place log-softmax on d_out rows 32..2047
__global__ __launch_bounds__(256) void k_lsm(float* __restrict__ out) {
    long row = 32 + blockIdx.x;
    float* p = out + row*32000L;
    float4* p4 = (float4*)p;
    int tid = threadIdx.x;
    __shared__ float sm[4];
    __shared__ float ss[4];
    float m = -1e30f;
    for (int i = tid; i < 8000; i += 256) {
        float4 v = p4[i];
        m = fmaxf(m, fmaxf(fmaxf(v.x, v.y), fmaxf(v.z, v.w)));
    }
    for (int off = 32; off; off >>= 1) m = fmaxf(m, __shfl_xor(m, off));
    if ((tid & 63) == 0) sm[tid >> 6] = m;
    __syncthreads();
    m = fmaxf(fmaxf(sm[0], sm[1]), fmaxf(sm[2], sm[3]));
    float s = 0;
    for (int i = tid; i < 8000; i += 256) {
        float4 v = p4[i];
        s += expf(v.x - m) + expf(v.y - m) + expf(v.z - m) + expf(v.w - m);
    }
    for (int off = 32; off; off >>= 1) s += __shfl_xor(s, off);
    if ((tid & 63) == 0) ss[tid >> 6] = s;
    __syncthreads();
    s = ss[0] + ss[1] + ss[2] + ss[3];
    float lse = m + logf(s);
    for (int i = tid; i < 8000; i += 256) {
        float4 v = p4[i];
        v.x -= lse; v.y -= lse; v.z -= lse; v.w -= lse;
        p4[i] = v;
    }
}

// ---------------- launch ----------------

extern "C" void kernel_launch(void* const* d_in, const int* in_sizes, int n_in,
                              void* d_out, int out_size, void* d_ws, size_t ws_size,
                              hipStream_t stream) {
    const float* eemb  = (const float*)d_in[0];
    const float* ewihf = (const float*)d_in[1];
    const float* ewhhf = (const float*)d_in[2];
    const float* ebf   = (const float*)d_in[3];
    const float* ewihb = (const float*)d_in[4];
    const float* ewhhb = (const float*)d_in[5];
    const float* ebb   = (const float*)d_in[6];
    const float* awi   = (const float*)d_in[7];
    const float* awo   = (const float*)d_in[8];
    const float* dwih  = (const float*)d_in[9];
    const float* dwhh  = (const float*)d_in[10];
    const float* db    = (const float*)d_in[11];
    const float* demb  = (const float*)d_in[12];
    const float* genw  = (const float*)d_in[13];
    const float* genb  = (const float*)d_in[14];
    const int* srci    = (const int*)d_in[15];
    const int* trgi    = (const int*)d_in[16];
    float* out = (float*)d_out;

    float* F = (float*)d_ws;
    int*   bars = (int*)F;                 // 256 counters  [0,256)
    float* cfin = F + 256;                 // 32768 floats  [256,33024)
    u16*   U    = (u16*)(F + 33024);       // bf16 region

    u16* Xf_    = U;                       // 2048x2048
    u16* Xb_    = U + 4194304u;            // 2048x2048
    u16* Xe_    = U + 8388608u;            // 2016x4096
    u16* WencB  = U + 16646144u;           // 2 x 2048x512
    u16* awiTB  = U + 18743296u;           // 1024x1024
    u16* awoB   = U + 19791872u;           // 1024x2048
    u16* WdecB  = U + 21889024u;           // 4096x2048
    u16* genw_b = U + 30277632u;           // 32000x1024
    u16* encBX  = U + 63045632u;           // 65 x 32x1024
    u16* Hd     = U + 65175552u;           // 65 x 32x1024
    u16* Stb    = U + 67305472u;           // 63 x 32x1024
    u16* Ctb    = U + 69369856u;           // 63 x 32x1024
    u16* encPB  = U + 71434240u;           // 2048x1024

    // barrier counters + t=0 output rows
    k_zero<<<1, 256, 0, stream>>>(F, 256);
    k_zero<<<2048, 256, 0, stream>>>(out, 1024000L);

    // input projections (gathered embedding @ W_ih^T + b), bf16 gate-packed
    k_xw<<<dim3(32, 64), 256, 0, stream>>>(eemb, srci, ewihf, 300, 0, ebf, Xf_, 2048, 511, 9);
    k_xw<<<dim3(32, 64), 256, 0, stream>>>(eemb, srci, ewihb, 300, 0, ebb, Xb_, 2048, 511, 9);
    k_xw<<<dim3(64, 63), 256, 0, stream>>>(demb, trgi, dwih, 1324, 1024, db, Xe_, 4096, 1023, 10);

    // weight conversions to bf16
    k_wenc<<<4096, 256, 0, stream>>>(ewhhf, WencB);
    k_wenc<<<4096, 256, 0, stream>>>(ewhhb, WencB + 1048576u);
    k_awiT<<<4096, 256, 0, stream>>>(awi, awiTB);
    k_f2b<<<2048, 256, 0, stream>>>((const float4*)awo, (ushort4*)awoB, 524288L);
    k_wdec<<<8192, 256, 0, stream>>>(dwih, dwhh, WdecB);
    k_f2b<<<8192, 256, 0, stream>>>((const float4*)genw, (ushort4*)genw_b, 8192000L);

    // persistent encoder + decoder
    k_seq<<<NBLK, 512, 0, stream>>>(Xf_, Xb_, Xe_, WencB, awiTB, awoB, WdecB,
                                    encBX, Hd, Stb, Ctb, encPB, cfin, bars);

    // batched generator + log-softmax
    k_gemm_gen<<<4000, 256, 0, stream>>>((const short*)(Hd + 32768u), (const short*)genw_b, genb, out);
    k_lsm<<<2016, 256, 0, stream>>>(out);
}

// Round 4
// 4936.845 us; speedup vs baseline: 5.0329x; 1.1012x over previous
//
#include <hip/hip_runtime.h>

typedef __attribute__((ext_vector_type(8))) short short8;
typedef __attribute__((ext_vector_type(4))) float f32x4;
typedef unsigned short u16;
typedef unsigned int u32;

#define NBLK 64

static __device__ __forceinline__ float sigf(float x){ return 1.0f/(1.0f+expf(-x)); }

static __device__ __forceinline__ u16 f2b(float f){
    u32 u = __float_as_uint(f);
    u += 0x7FFFu + ((u>>16)&1u);   // RNE
    return (u16)(u>>16);
}
static __device__ __forceinline__ float us2f(u16 s){ return __uint_as_float(((u32)s)<<16); }
static __device__ __forceinline__ float b2f_lo(u32 u){ return __uint_as_float(u<<16); }
static __device__ __forceinline__ float b2f_hi(u32 u){ return __uint_as_float(u & 0xffff0000u); }

// Device-scope write-through stores (agent scope, sc1): bypass L2, land in LLC.
// Used for ALL data consumed by other blocks inside k_seq -> no cache flush needed.
static __device__ __forceinline__ void st_wt_u16(u16* p, u16 v) {
    asm volatile("global_store_short %0, %1, off sc1" :: "v"(p), "v"((u32)v) : "memory");
}
static __device__ __forceinline__ void st_wt_u32(u32* p, u32 v) {
    asm volatile("global_store_dword %0, %1, off sc1" :: "v"(p), "v"(v) : "memory");
}
static __device__ __forceinline__ void st_wt_f32(float* p, float v) {
    asm volatile("global_store_dword %0, %1, off sc1" :: "v"(p), "v"(v) : "memory");
}

// Grid barrier: no cache maintenance at all.
//  - __syncthreads drains each wave's vmcnt (WT stores complete in LLC)
//  - single-use relaxed agent-scope counter + spin
//  - correctness relies on fresh-address discipline for all cross-block data
static __device__ __forceinline__ void gbar(int* ctr) {
    __syncthreads();
    if (threadIdx.x == 0) {
        __hip_atomic_fetch_add(ctr, 1, __ATOMIC_RELAXED, __HIP_MEMORY_SCOPE_AGENT);
        while (__hip_atomic_load(ctr, __ATOMIC_RELAXED, __HIP_MEMORY_SCOPE_AGENT) < NBLK)
            __builtin_amdgcn_s_sleep(1);
    }
    __syncthreads();
}

// ---------------- utility / conversion kernels ----------------

__global__ __launch_bounds__(256) void k_zero(float* __restrict__ p, long n) {
    for (long i = (long)blockIdx.x*256 + threadIdx.x; i < n; i += (long)gridDim.x*256) p[i] = 0.0f;
}

__global__ __launch_bounds__(256) void k_f2b(const float4* __restrict__ src,
                                             ushort4* __restrict__ dst, long n4) {
    for (long i = (long)blockIdx.x*256 + threadIdx.x; i < n4; i += (long)gridDim.x*256) {
        float4 v = src[i];
        ushort4 u;
        u.x = f2b(v.x); u.y = f2b(v.y); u.z = f2b(v.z); u.w = f2b(v.w);
        dst[i] = u;
    }
}

// WencB[(j*4+q)*512 + k] = bf16(whh[(q*512+j)*512 + k])
__global__ __launch_bounds__(256) void k_wenc(const float* __restrict__ whh, u16* __restrict__ dst) {
    int i = blockIdx.x*256 + threadIdx.x;           // 1,048,576
    int n = i >> 9, k = i & 511;
    int j = n >> 2, q = n & 3;
    dst[i] = f2b(whh[(size_t)(q*512 + j)*512 + k]);
}

// awiTB[kcol*1024 + n] = bf16(awi[n*1024 + kcol])
__global__ __launch_bounds__(256) void k_awiT(const float* __restrict__ awi, u16* __restrict__ dst) {
    int i = blockIdx.x*256 + threadIdx.x;           // 1,048,576
    int kcol = i >> 10, n = i & 1023;
    dst[i] = f2b(awi[(size_t)n*1024 + kcol]);
}

// WdecB[(j*4+q)*2048 + k] = bf16( k<1024 ? dwih[(q*1024+j)*1324+k] : dwhh[(q*1024+j)*1024+k-1024] )
__global__ __launch_bounds__(256) void k_wdec(const float* __restrict__ dwih,
                                              const float* __restrict__ dwhh,
                                              u16* __restrict__ dst) {
    for (long i = (long)blockIdx.x*256 + threadIdx.x; i < 8388608L; i += (long)gridDim.x*256) {
        int n = (int)(i >> 11), k = (int)(i & 2047);
        int j = n >> 2, q = n & 3;
        float v = (k < 1024) ? dwih[(size_t)(q*1024 + j)*1324 + k]
                             : dwhh[(size_t)(q*1024 + j)*1024 + (k - 1024)];
        dst[i] = f2b(v);
    }
}

// X = gather(table, idx) @ W[:, koff:koff+300]^T + bias, stored bf16, gate-packed col = (jj&jmask)*4 | (jj>>jshift)
__global__ __launch_bounds__(256) void k_xw(const float* __restrict__ table,
                                            const int* __restrict__ idx,
                                            const float* __restrict__ W,
                                            int wstride, int koff,
                                            const float* __restrict__ bias,
                                            u16* __restrict__ outU, int N,
                                            int jmask, int jshift) {
    __shared__ float Xs[32][300];
    int m0 = blockIdx.y * 32;
    int j0 = blockIdx.x * 64;
    for (int i = threadIdx.x; i < 32*300; i += 256) {
        int r = i/300, c = i - r*300;
        Xs[r][c] = table[(size_t)idx[m0+r]*300 + c];
    }
    __syncthreads();
    int tx = threadIdx.x & 63, ty = threadIdx.x >> 6;
    int jj = j0 + tx;
    const float* wr = W + (size_t)jj*wstride + koff;
    float acc[8] = {0,0,0,0,0,0,0,0};
    for (int k = 0; k < 300; ++k) {
        float w = wr[k];
#pragma unroll
        for (int mi = 0; mi < 8; ++mi) acc[mi] += Xs[ty*8+mi][k] * w;
    }
    float bv = bias[jj];
    int col = ((jj & jmask) << 2) | (jj >> jshift);
#pragma unroll
    for (int mi = 0; mi < 8; ++mi)
        outU[(size_t)(m0 + ty*8 + mi)*N + col] = f2b(acc[mi] + bv);
}

// ---------------- persistent recurrence kernel ----------------
// 64 blocks x 512 threads (8 waves). All matmuls via MFMA in bf16.
// Fresh-address discipline + WT stores: every cross-block datum has a unique
// per-step slot and is stored with sc1 (direct to LLC).
__global__ __launch_bounds__(512) void k_seq(
    const u16* __restrict__ Xf, const u16* __restrict__ Xb, const u16* __restrict__ Xe,
    const u16* __restrict__ WencB, const u16* __restrict__ awiTB,
    const u16* __restrict__ awoB, const u16* __restrict__ WdecB,
    u16* __restrict__ encBX,   // 65 slots [32][1024]: slot 0 zeros, slot s+1 = enc_out[s] (bf16)
    u16* __restrict__ Hd,      // 65 slots [32][1024]: slot 0 init hidden, slot t+1 = h after dec step t, slot 64 zeros
    u16* __restrict__ Stb,     // 63 slots [32][1024] s_tilde
    u16* __restrict__ Ctb,     // 63 slots [32][1024] c_t
    u16* __restrict__ encPB,   // [2048][1024] enc_out @ attn_wi (bf16)
    float* __restrict__ cfin,  // [2][32][512] final encoder c
    int* bars)
{
    __shared__ float SH[2304];
    const int tid = threadIdx.x;
    const int bid = blockIdx.x;
    const int wv = tid >> 6, lane = tid & 63;
    const int gwave = bid*8 + wv;
    const int lr = lane & 15, lk8 = (lane >> 4)*8;
    const int b_l = lane & 15, jjq = lane >> 4;
    const int gt = bid*512 + tid;
    int bi = 0;

    // ---- P0: zero encBX slot 0 ----
    if (gt < 16384) st_wt_u32((u32*)encBX + gt, 0u);
    gbar(bars + bi++);

    // ---- encoder: 64 steps ----
    {
        const int dir = gwave >> 8;
        const int mt = (gwave >> 7) & 1;
        const int nt = gwave & 127;
        const int m0 = mt*16, n0 = nt*16;
        const u16* Bw = WencB + (size_t)dir*1048576 + (size_t)(n0+lr)*512 + lk8;
        const u16* Xd = dir ? Xb : Xf;
        float* T = SH + wv*272;
        const int bb = m0 + b_l;
        const int j = nt*4 + jjq;
        float creg = 0.f;
        for (int t = 0; t < 64; ++t) {
            const int rslot = (t==0) ? 0 : (dir ? (65-t) : t);
            const u16* Ah = encBX + (size_t)rslot*32768 + (size_t)(m0+lr)*1024 + dir*512 + lk8;
            f32x4 acc = {0.f,0.f,0.f,0.f};
#pragma unroll
            for (int i = 0; i < 16; ++i) {
                short8 av = *(const short8*)(Ah + i*32);
                short8 bv = *(const short8*)(Bw + i*32);
                acc = __builtin_amdgcn_mfma_f32_16x16x32_bf16(av, bv, acc, 0, 0, 0);
            }
            {
                const int rb = (lane>>4)*4;
#pragma unroll
                for (int r = 0; r < 4; ++r) T[(rb+r)*17 + (lane&15)] = acc[r];
            }
            __builtin_amdgcn_sched_barrier(0);
            const int s = dir ? (63-t) : t;
            ushort4 xr = *(const ushort4*)(Xd + (size_t)(s*32+bb)*2048 + n0 + jjq*4);
            float gi = T[b_l*17 + jjq*4 + 0] + us2f(xr.x);
            float gf = T[b_l*17 + jjq*4 + 1] + us2f(xr.y);
            float gg = T[b_l*17 + jjq*4 + 2] + us2f(xr.z);
            float go = T[b_l*17 + jjq*4 + 3] + us2f(xr.w);
            float c2 = sigf(gf)*creg + sigf(gi)*tanhf(gg);
            float h2 = sigf(go)*tanhf(c2);
            creg = c2;
            st_wt_u16(encBX + (size_t)(s+1)*32768 + (size_t)bb*1024 + dir*512 + j, f2b(h2));
            gbar(bars + bi++);
        }
        st_wt_f32(cfin + dir*16384 + bb*512 + j, creg);
    }

    // ---- pack: Hd[0] = interleaved final h; zero Hd[64] (generator pad) ----
    {
        int b = gt >> 10, jj2 = gt & 1023;
        int d = jj2 & 1, k = jj2 >> 1;
        st_wt_u16(Hd + (size_t)b*1024 + jj2,
                  encBX[(size_t)(d ? 1 : 64)*32768 + (size_t)b*1024 + d*512 + k]);
        st_wt_u16(Hd + (size_t)64*32768 + gt, 0);
    }
    gbar(bars + bi++);

    // ---- encP = enc_out @ attn_wi  (M=2048, N=1024, K=1024) ----
    {
        const u16* Abase = encBX + 32768;
        for (int ii = 0; ii < 16; ++ii) {
            int id = gwave*16 + ii;
            int mt2 = id >> 6, nt2 = id & 63;
            int m0 = mt2*16, n0 = nt2*16;
            const u16* Ar = Abase + (size_t)(m0+lr)*1024 + lk8;
            const u16* Br = awiTB + (size_t)(n0+lr)*1024 + lk8;
            f32x4 acc = {0.f,0.f,0.f,0.f};
#pragma unroll 8
            for (int i = 0; i < 32; ++i) {
                short8 av = *(const short8*)(Ar + i*32);
                short8 bv = *(const short8*)(Br + i*32);
                acc = __builtin_amdgcn_mfma_f32_16x16x32_bf16(av, bv, acc, 0, 0, 0);
            }
            int col = n0 + (lane&15);
            int rb = m0 + (lane>>4)*4;
#pragma unroll
            for (int r = 0; r < 4; ++r)
                st_wt_u16(encPB + (size_t)(rb+r)*1024 + col, f2b(acc[r]));
        }
    }
    gbar(bars + bi++);

    // ---- decoder: c-init from cfin (c lives in registers) ----
    const int nt4 = gwave >> 1, mt4 = gwave & 1;
    const int n0d = nt4*16, m0d = mt4*16;
    const int bbd = m0d + b_l;
    const int jd = nt4*4 + jjq;
    float cdec = cfin[(jd&1)*16384 + bbd*512 + (jd>>1)];

    // ---- decoder: 63 steps x {P2 attn, P3 c_t, P4 gates+cell} ----
    for (int t = 0; t < 63; ++t) {
        // P2: scores = encP . h ; softmax(S=64); s_tilde = sum_s p_s * enc_out[s]
        if (bid < 32) {
            const int bbb = bid;
            float* hsh = SH; float* red = SH + 1024; float* sc = SH + 1536;
            {
                u32 u = ((const u32*)Hd)[(size_t)t*16384 + bbb*512 + tid];
                hsh[2*tid]   = b2f_lo(u);
                hsh[2*tid+1] = b2f_hi(u);
            }
            __syncthreads();
            {
                int s = tid >> 3, p = tid & 7;
                const uint4* ep = (const uint4*)(encPB + (size_t)(s*32+bbb)*1024 + p*128);
                const float* hk = hsh + p*128;
                float a0=0,a1=0,a2=0,a3=0;
#pragma unroll 4
                for (int q8 = 0; q8 < 16; ++q8) {
                    uint4 u = ep[q8];
                    a0 += b2f_lo(u.x)*hk[q8*8+0] + b2f_hi(u.x)*hk[q8*8+1];
                    a1 += b2f_lo(u.y)*hk[q8*8+2] + b2f_hi(u.y)*hk[q8*8+3];
                    a2 += b2f_lo(u.z)*hk[q8*8+4] + b2f_hi(u.z)*hk[q8*8+5];
                    a3 += b2f_lo(u.w)*hk[q8*8+6] + b2f_hi(u.w)*hk[q8*8+7];
                }
                red[tid] = (a0+a1)+(a2+a3);
            }
            __syncthreads();
            if (tid < 64) {
                float v = 0;
#pragma unroll
                for (int pp = 0; pp < 8; ++pp) v += red[tid*8+pp];
                float m = v;
                for (int off = 32; off; off >>= 1) m = fmaxf(m, __shfl_xor(m, off));
                float e = expf(v - m);
                float ss = e;
                for (int off = 32; off; off >>= 1) ss += __shfl_xor(ss, off);
                sc[tid] = e / ss;
            }
            __syncthreads();
            {
                float st0 = 0, st1 = 0;
                const u32* eb = (const u32*)encBX + 16384 + bbb*512 + tid;  // slot s2+1
#pragma unroll 4
                for (int s2 = 0; s2 < 64; ++s2) {
                    u32 u = eb[(size_t)s2*16384];
                    float w = sc[s2];
                    st0 += w*b2f_lo(u); st1 += w*b2f_hi(u);
                }
                u32 pk = (u32)f2b(st0) | ((u32)f2b(st1) << 16);
                st_wt_u32((u32*)Stb + (size_t)t*16384 + bbb*512 + tid, pk);
            }
        }
        gbar(bars + bi++);

        // P3: c_t = tanh([s_tilde, h] @ awo^T)  (K split 4 ways across waves)
        {
            const int nt3 = bid;
            const int mt3 = wv >> 2, kq = wv & 3;
            const int m0 = mt3*16, n0 = nt3*16;
            const u16* Br = awoB + (size_t)(n0+lr)*2048 + kq*512 + lk8;
            const u16* As  = Stb + (size_t)t*32768 + (size_t)(m0+lr)*1024 + kq*512 + lk8;
            const u16* Ah2 = Hd  + (size_t)t*32768 + (size_t)(m0+lr)*1024 + (kq-2)*512 + lk8;
            const u16* Ar = (kq < 2) ? As : Ah2;
            f32x4 acc = {0.f,0.f,0.f,0.f};
#pragma unroll 4
            for (int i = 0; i < 16; ++i) {
                short8 av = *(const short8*)(Ar + i*32);
                short8 bv = *(const short8*)(Br + i*32);
                acc = __builtin_amdgcn_mfma_f32_16x16x32_bf16(av, bv, acc, 0, 0, 0);
            }
            float* PH = SH + wv*256;
#pragma unroll
            for (int r = 0; r < 4; ++r) PH[lane*4 + r] = acc[r];
            __syncthreads();
            if (kq == 0) {
#pragma unroll
                for (int r = 0; r < 4; ++r) {
                    float sum = SH[wv*256 + lane*4 + r] + SH[(wv+1)*256 + lane*4 + r]
                              + SH[(wv+2)*256 + lane*4 + r] + SH[(wv+3)*256 + lane*4 + r];
                    int bq = m0 + (lane>>4)*4 + r;
                    st_wt_u16(Ctb + (size_t)t*32768 + (size_t)bq*1024 + n0 + (lane&15),
                              f2b(tanhf(sum)));
                }
            }
        }
        gbar(bars + bi++);

        // P4: gates = [c_t, h] @ Wdec^T + Xe ; cell update; h -> Hd[t+1]
        {
            const u16* Br  = WdecB + (size_t)(n0d+lr)*2048 + lk8;
            const u16* Ac  = Ctb + (size_t)t*32768 + (size_t)(m0d+lr)*1024 + lk8;
            const u16* Ah3 = Hd  + (size_t)t*32768 + (size_t)(m0d+lr)*1024 + lk8;
            f32x4 acc = {0.f,0.f,0.f,0.f};
#pragma unroll 4
            for (int i = 0; i < 32; ++i) {
                short8 av = *(const short8*)(Ac + i*32);
                short8 bv = *(const short8*)(Br + i*32);
                acc = __builtin_amdgcn_mfma_f32_16x16x32_bf16(av, bv, acc, 0, 0, 0);
            }
#pragma unroll 4
            for (int i = 0; i < 32; ++i) {
                short8 av = *(const short8*)(Ah3 + i*32);
                short8 bv = *(const short8*)(Br + 1024 + i*32);
                acc = __builtin_amdgcn_mfma_f32_16x16x32_bf16(av, bv, acc, 0, 0, 0);
            }
            float* T = SH + wv*272;
            {
                const int rb = (lane>>4)*4;
#pragma unroll
                for (int r = 0; r < 4; ++r) T[(rb+r)*17 + (lane&15)] = acc[r];
            }
            __builtin_amdgcn_sched_barrier(0);
            ushort4 xr = *(const ushort4*)(Xe + (size_t)(t*32+bbd)*4096 + n0d + jjq*4);
            float gi = T[b_l*17 + jjq*4 + 0] + us2f(xr.x);
            float gf = T[b_l*17 + jjq*4 + 1] + us2f(xr.y);
            float gg = T[b_l*17 + jjq*4 + 2] + us2f(xr.z);
            float go = T[b_l*17 + jjq*4 + 3] + us2f(xr.w);
            float c2 = sigf(gf)*cdec + sigf(gi)*tanhf(gg);
            float h2 = sigf(go)*tanhf(c2);
            cdec = c2;
            st_wt_u16(Hd + (size_t)(t+1)*32768 + (size_t)bbd*1024 + jd, f2b(h2));
        }
        gbar(bars + bi++);
    }
}

// ---------------- generator GEMM (bf16 MFMA) ----------------
__global__ __launch_bounds__(256) void k_gemm_gen(const short* __restrict__ A,
                                                  const short* __restrict__ B,
                                                  const float* __restrict__ genb,
                                                  float* __restrict__ out) {
    int wave = threadIdx.x >> 6;
    int lane = threadIdx.x & 63;
    int tile = blockIdx.x * 4 + wave;  // 16000 tiles = 32 m x 500 n
    int mt = tile & 31;
    int nt = tile >> 5;
    int m0 = mt*64, n0 = nt*64;
    int lr = lane & 15;
    int lk = (lane >> 4)*8;
    f32x4 acc[4][4] = {};
    for (int k0 = 0; k0 < 1024; k0 += 32) {
        short8 a[4], bfr[4];
#pragma unroll
        for (int mi = 0; mi < 4; ++mi)
            a[mi] = *(const short8*)(A + (long)(m0 + mi*16 + lr)*1024 + k0 + lk);
#pragma unroll
        for (int ni = 0; ni < 4; ++ni)
            bfr[ni] = *(const short8*)(B + (long)(n0 + ni*16 + lr)*1024 + k0 + lk);
#pragma unroll
        for (int mi = 0; mi < 4; ++mi)
#pragma unroll
            for (int ni = 0; ni < 4; ++ni)
                acc[mi][ni] = __builtin_amdgcn_mfma_f32_16x16x32_bf16(a[mi], bfr[ni], acc[mi][ni], 0, 0, 0);
    }
    int dcol = lane & 15;
    int drow = (lane >> 4)*4;
#pragma unroll
    for (int mi = 0; mi < 4; ++mi) {
        int mbase = m0 + mi*16 + drow;
#pragma unroll
        for (int ni = 0; ni < 4; ++ni) {
            int n = n0 + ni*16 + dcol;
            float bv = genb[n];
            f32x4 v = acc[mi][ni];
#pragma unroll
            for (int r = 0; r < 4; ++r) {
                int m = mbase + r;
                if (m < 2016) out[(long)(m + 32)*32000 + n] = v[r] + bv;
            }
        }
    }
}

// in-place log-softmax on d_out rows 32..2047
__global__ __launch_bounds__(256) void k_lsm(float* __restrict__ out) {
    long row = 32 + blockIdx.x;
    float* p = out + row*32000L;
    float4* p4 = (float4*)p;
    int tid = threadIdx.x;
    __shared__ float sm[4];
    __shared__ float ss[4];
    float m = -1e30f;
    for (int i = tid; i < 8000; i += 256) {
        float4 v = p4[i];
        m = fmaxf(m, fmaxf(fmaxf(v.x, v.y), fmaxf(v.z, v.w)));
    }
    for (int off = 32; off; off >>= 1) m = fmaxf(m, __shfl_xor(m, off));
    if ((tid & 63) == 0) sm[tid >> 6] = m;
    __syncthreads();
    m = fmaxf(fmaxf(sm[0], sm[1]), fmaxf(sm[2], sm[3]));
    float s = 0;
    for (int i = tid; i < 8000; i += 256) {
        float4 v = p4[i];
        s += expf(v.x - m) + expf(v.y - m) + expf(v.z - m) + expf(v.w - m);
    }
    for (int off = 32; off; off >>= 1) s += __shfl_xor(s, off);
    if ((tid & 63) == 0) ss[tid >> 6] = s;
    __syncthreads();
    s = ss[0] + ss[1] + ss[2] + ss[3];
    float lse = m + logf(s);
    for (int i = tid; i < 8000; i += 256) {
        float4 v = p4[i];
        v.x -= lse; v.y -= lse; v.z -= lse; v.w -= lse;
        p4[i] = v;
    }
}

// ---------------- launch ----------------

extern "C" void kernel_launch(void* const* d_in, const int* in_sizes, int n_in,
                              void* d_out, int out_size, void* d_ws, size_t ws_size,
                              hipStream_t stream) {
    const float* eemb  = (const float*)d_in[0];
    const float* ewihf = (const float*)d_in[1];
    const float* ewhhf = (const float*)d_in[2];
    const float* ebf   = (const float*)d_in[3];
    const float* ewihb = (const float*)d_in[4];
    const float* ewhhb = (const float*)d_in[5];
    const float* ebb   = (const float*)d_in[6];
    const float* awi   = (const float*)d_in[7];
    const float* awo   = (const float*)d_in[8];
    const float* dwih  = (const float*)d_in[9];
    const float* dwhh  = (const float*)d_in[10];
    const float* db    = (const float*)d_in[11];
    const float* demb  = (const float*)d_in[12];
    const float* genw  = (const float*)d_in[13];
    const float* genb  = (const float*)d_in[14];
    const int* srci    = (const int*)d_in[15];
    const int* trgi    = (const int*)d_in[16];
    float* out = (float*)d_out;

    float* F = (float*)d_ws;
    int*   bars = (int*)F;                 // 256 counters  [0,256)
    float* cfin = F + 256;                 // 32768 floats  [256,33024)
    u16*   U    = (u16*)(F + 33024);       // bf16 region

    u16* Xf_    = U;                       // 2048x2048
    u16* Xb_    = U + 4194304u;            // 2048x2048
    u16* Xe_    = U + 8388608u;            // 2016x4096
    u16* WencB  = U + 16646144u;           // 2 x 2048x512
    u16* awiTB  = U + 18743296u;           // 1024x1024
    u16* awoB   = U + 19791872u;           // 1024x2048
    u16* WdecB  = U + 21889024u;           // 4096x2048
    u16* genw_b = U + 30277632u;           // 32000x1024
    u16* encBX  = U + 63045632u;           // 65 x 32x1024
    u16* Hd     = U + 65175552u;           // 65 x 32x1024
    u16* Stb    = U + 67305472u;           // 63 x 32x1024
    u16* Ctb    = U + 69369856u;           // 63 x 32x1024
    u16* encPB  = U + 71434240u;           // 2048x1024

    // barrier counters + t=0 output rows
    k_zero<<<1, 256, 0, stream>>>(F, 256);
    k_zero<<<2048, 256, 0, stream>>>(out, 1024000L);

    // input projections (gathered embedding @ W_ih^T + b), bf16 gate-packed
    k_xw<<<dim3(32, 64), 256, 0, stream>>>(eemb, srci, ewihf, 300, 0, ebf, Xf_, 2048, 511, 9);
    k_xw<<<dim3(32, 64), 256, 0, stream>>>(eemb, srci, ewihb, 300, 0, ebb, Xb_, 2048, 511, 9);
    k_xw<<<dim3(64, 63), 256, 0, stream>>>(demb, trgi, dwih, 1324, 1024, db, Xe_, 4096, 1023, 10);

    // weight conversions to bf16
    k_wenc<<<4096, 256, 0, stream>>>(ewhhf, WencB);
    k_wenc<<<4096, 256, 0, stream>>>(ewhhb, WencB + 1048576u);
    k_awiT<<<4096, 256, 0, stream>>>(awi, awiTB);
    k_f2b<<<2048, 256, 0, stream>>>((const float4*)awo, (ushort4*)awoB, 524288L);
    k_wdec<<<8192, 256, 0, stream>>>(dwih, dwhh, WdecB);
    k_f2b<<<8192, 256, 0, stream>>>((const float4*)genw, (ushort4*)genw_b, 8192000L);

    // persistent encoder + decoder
    k_seq<<<NBLK, 512, 0, stream>>>(Xf_, Xb_, Xe_, WencB, awiTB, awoB, WdecB,
                                    encBX, Hd, Stb, Ctb, encPB, cfin, bars);

    // batched generator + log-softmax
    k_gemm_gen<<<4000, 256, 0, stream>>>((const short*)(Hd + 32768u), (const short*)genw_b, genb, out);
    k_lsm<<<2016, 256, 0, stream>>>(out);
}